// Round 1
// baseline (217.982 us; speedup 1.0000x reference)
//
#include <hip/hip_runtime.h>
#include <hip/hip_bf16.h>

// SmoothLDDTLoss: b=2, n=4096
// inputs: pred_coords f32[2,4096,3], true_coords f32[2,4096,3],
//         is_dna i32[2,4096], is_rna i32[2,4096], coords_mask i32[2,4096]
// output: scalar f32 = 1 - mean_b(lddt_b)

#define NRES 4096
#define NBATCH 2

__launch_bounds__(256)
__global__ void lddt_pairs(const float* __restrict__ pred,
                           const float* __restrict__ truec,
                           const int* __restrict__ dna,
                           const int* __restrict__ rna,
                           const int* __restrict__ cm,
                           float* __restrict__ acc)  // [0..1] eps sums, [2..3] counts
{
    const int b = blockIdx.y;
    const int i = blockIdx.x;
    const int base = b * NRES;

    // whole row masked out -> contributes nothing (uniform branch, before any sync)
    if (cm[base + i] == 0) return;

    const float* tb = truec + (size_t)base * 3;
    const float* pb = pred  + (size_t)base * 3;

    const float tix = tb[3*i+0], tiy = tb[3*i+1], tiz = tb[3*i+2];
    const float pix = pb[3*i+0], piy = pb[3*i+1], piz = pb[3*i+2];
    const bool  nuci = (dna[base+i] | rna[base+i]) != 0;

    float s = 0.0f;   // sum of eps*mask
    float c = 0.0f;   // count of mask (integer-valued, exact in f32 below 2^24)

    for (int j = threadIdx.x; j < NRES; j += 256) {
        float tjx = tb[3*j+0], tjy = tb[3*j+1], tjz = tb[3*j+2];
        float dx = tix - tjx, dy = tiy - tjy, dz = tiz - tjz;
        float dt = sqrtf(dx*dx + dy*dy + dz*dz);

        bool  nucj   = (dna[base+j] | rna[base+j]) != 0;
        float cutoff = (nuci & nucj) ? 30.0f : 15.0f;
        bool  msk    = (dt < cutoff) & (j != i) & (cm[base+j] != 0);
        float mf     = msk ? 1.0f : 0.0f;

        float pjx = pb[3*j+0], pjy = pb[3*j+1], pjz = pb[3*j+2];
        float ex = pix - pjx, ey = piy - pjy, ez = piz - pjz;
        float dp = sqrtf(ex*ex + ey*ey + ez*ez);

        float diff = fabsf(dt - dp);
        // sigmoid(a - diff) = 1 / (1 + e^{-a} * e^{diff}); one exp for all four terms
        float E = __expf(diff);
        float e = 1.0f / (1.0f + 0.60653065971f * E)    // a = 0.5
                + 1.0f / (1.0f + 0.36787944117f * E)    // a = 1.0
                + 1.0f / (1.0f + 0.13533528324f * E)    // a = 2.0
                + 1.0f / (1.0f + 0.01831563889f * E);   // a = 4.0

        s += mf * 0.25f * e;
        c += mf;
    }

    // wave (64-lane) reduction
    #pragma unroll
    for (int o = 32; o > 0; o >>= 1) {
        s += __shfl_down(s, o, 64);
        c += __shfl_down(c, o, 64);
    }

    __shared__ float red_s[4];
    __shared__ float red_c[4];
    const int wid  = threadIdx.x >> 6;
    const int lane = threadIdx.x & 63;
    if (lane == 0) { red_s[wid] = s; red_c[wid] = c; }
    __syncthreads();

    if (threadIdx.x == 0) {
        float ts = red_s[0] + red_s[1] + red_s[2] + red_s[3];
        float tc = red_c[0] + red_c[1] + red_c[2] + red_c[3];
        atomicAdd(&acc[b], ts);
        atomicAdd(&acc[NBATCH + b], tc);
    }
}

__global__ void lddt_final(const float* __restrict__ acc, float* __restrict__ out)
{
    float l0 = acc[0] / fmaxf(acc[NBATCH + 0], 1.0f);
    float l1 = acc[1] / fmaxf(acc[NBATCH + 1], 1.0f);
    out[0] = 1.0f - 0.5f * (l0 + l1);
}

extern "C" void kernel_launch(void* const* d_in, const int* in_sizes, int n_in,
                              void* d_out, int out_size, void* d_ws, size_t ws_size,
                              hipStream_t stream) {
    const float* pred  = (const float*)d_in[0];
    const float* truec = (const float*)d_in[1];
    const int*   dna   = (const int*)d_in[2];
    const int*   rna   = (const int*)d_in[3];
    const int*   cmask = (const int*)d_in[4];
    float* out = (float*)d_out;
    float* acc = (float*)d_ws;

    hipMemsetAsync(acc, 0, 2 * NBATCH * sizeof(float), stream);

    dim3 grid(NRES, NBATCH);
    lddt_pairs<<<grid, 256, 0, stream>>>(pred, truec, dna, rna, cmask, acc);
    lddt_final<<<1, 1, 0, stream>>>(acc, out);
}

// Round 2
// 75.852 us; speedup vs baseline: 2.8738x; 2.8738x over previous
//
#include <hip/hip_runtime.h>
#include <hip/hip_bf16.h>

// SmoothLDDTLoss: b=2, n=4096
// inputs: pred_coords f32[2,4096,3], true_coords f32[2,4096,3],
//         is_dna i32[2,4096], is_rna i32[2,4096], coords_mask i32[2,4096]
// output: scalar f32 = 1 - mean_b(lddt_b)
//
// Key identity: sigma(.5-d)+sigma(1-d)+sigma(2-d)+sigma(4-d) = t*Q'(t)/Q(t),
// t = exp(-d), Q(t) = prod_k (1 + e^{a_k} t)  (exact algebra, 1 rcp instead of 4)

#define NRES 4096
#define NBATCH 2
#define TI 4

// Q coefficients: elementary symmetric polys of {e^0.5, e^1, e^2, e^4}
#define S1 66.35420923f
#define S2 678.60880385f
#define S3 2039.58217570f
#define S4 1808.04241445f
// Q'(t)/4 coefficients
#define QP1 16.58855231f
#define QP2 339.30440193f
#define QP3 1529.68663177f
#define QP4 1808.04241445f

__global__ void pack_kernel(const float* __restrict__ pred,
                            const float* __restrict__ truec,
                            const int* __restrict__ dna,
                            const int* __restrict__ rna,
                            const int* __restrict__ cm,
                            float4* __restrict__ tp,
                            float4* __restrict__ pp)
{
    int idx = blockIdx.x * 256 + threadIdx.x;
    if (idx >= NRES * NBATCH) return;
    float nuc = ((dna[idx] | rna[idx]) != 0) ? 1.0f : 0.0f;
    float cmf = (cm[idx] != 0) ? 1.0f : 0.0f;
    tp[idx] = make_float4(truec[3*idx+0], truec[3*idx+1], truec[3*idx+2], nuc);
    pp[idx] = make_float4(pred[3*idx+0],  pred[3*idx+1],  pred[3*idx+2],  cmf);
}

__launch_bounds__(256)
__global__ void lddt_main(const float4* __restrict__ tp,
                          const float4* __restrict__ pp,
                          float* __restrict__ acc)  // [0..1] eps sums, [2..3] counts
{
    const int b    = blockIdx.y;
    const int i0   = blockIdx.x * TI;
    const int base = b * NRES;

    float tix[TI], tiy[TI], tiz[TI];
    float pix[TI], piy[TI], piz[TI];
    float cHi[TI], cLo[TI];
    #pragma unroll
    for (int r = 0; r < TI; ++r) {
        float4 t4 = tp[base + i0 + r];
        float4 p4 = pp[base + i0 + r];
        tix[r] = t4.x; tiy[r] = t4.y; tiz[r] = t4.z;
        pix[r] = p4.x; piy[r] = p4.y; piz[r] = p4.z;
        bool cmi  = (p4.w != 0.0f);
        bool nuci = (t4.w != 0.0f);
        // cm_i folded into cutoffs: masked row -> cutoff -1 -> mask never true
        cHi[r] = cmi ? (nuci ? 30.0f : 15.0f) : -1.0f;
        cLo[r] = cmi ? 15.0f : -1.0f;
    }

    float s = 0.0f, c = 0.0f;

    for (int j = threadIdx.x; j < NRES; j += 256) {
        float4 t4 = tp[base + j];
        float4 p4 = pp[base + j];
        float  wj   = p4.w;               // cm_j as 1.0/0.0
        bool   nucj = (t4.w != 0.0f);

        #pragma unroll
        for (int r = 0; r < TI; ++r) {
            float dx = tix[r] - t4.x, dy = tiy[r] - t4.y, dz = tiz[r] - t4.z;
            float dt = __builtin_amdgcn_sqrtf(dx*dx + dy*dy + dz*dz);
            float ex = pix[r] - p4.x, ey = piy[r] - p4.y, ez = piz[r] - p4.z;
            float dp = __builtin_amdgcn_sqrtf(ex*ex + ey*ey + ez*ez);

            float cutoff = nucj ? cHi[r] : cLo[r];
            bool  msk    = (dt < cutoff) && (j != i0 + r);

            float diff = fabsf(dt - dp);
            float t = __expf(-diff);                       // native v_exp path
            float Q  = 1.0f + t*(S1 + t*(S2 + t*(S3 + t*S4)));
            float Qp = QP1 + t*(QP2 + t*(QP3 + t*QP4));    // Q'(t)/4
            float rq = __builtin_amdgcn_rcpf(Q);

            float mf = msk ? wj : 0.0f;
            s += (t * mf) * (Qp * rq);
            c += mf;
        }
    }

    // wave (64-lane) reduction
    #pragma unroll
    for (int o = 32; o > 0; o >>= 1) {
        s += __shfl_down(s, o, 64);
        c += __shfl_down(c, o, 64);
    }

    __shared__ float red_s[4];
    __shared__ float red_c[4];
    const int wid  = threadIdx.x >> 6;
    const int lane = threadIdx.x & 63;
    if (lane == 0) { red_s[wid] = s; red_c[wid] = c; }
    __syncthreads();

    if (threadIdx.x == 0) {
        float ts = red_s[0] + red_s[1] + red_s[2] + red_s[3];
        float tc = red_c[0] + red_c[1] + red_c[2] + red_c[3];
        atomicAdd(&acc[b], ts);
        atomicAdd(&acc[NBATCH + b], tc);
    }
}

__global__ void lddt_final(const float* __restrict__ acc, float* __restrict__ out)
{
    float l0 = acc[0] / fmaxf(acc[NBATCH + 0], 1.0f);
    float l1 = acc[1] / fmaxf(acc[NBATCH + 1], 1.0f);
    out[0] = 1.0f - 0.5f * (l0 + l1);
}

extern "C" void kernel_launch(void* const* d_in, const int* in_sizes, int n_in,
                              void* d_out, int out_size, void* d_ws, size_t ws_size,
                              hipStream_t stream) {
    const float* pred  = (const float*)d_in[0];
    const float* truec = (const float*)d_in[1];
    const int*   dna   = (const int*)d_in[2];
    const int*   rna   = (const int*)d_in[3];
    const int*   cmask = (const int*)d_in[4];
    float* out = (float*)d_out;

    char* ws = (char*)d_ws;
    float*  acc = (float*)ws;                         // 4 floats
    float4* tp  = (float4*)(ws + 1024);               // 2*4096*16 B
    float4* pp  = (float4*)(ws + 1024 + NBATCH*NRES*16);

    hipMemsetAsync(acc, 0, 2 * NBATCH * sizeof(float), stream);

    pack_kernel<<<(NRES*NBATCH + 255)/256, 256, 0, stream>>>(pred, truec, dna, rna, cmask, tp, pp);

    dim3 grid(NRES / TI, NBATCH);
    lddt_main<<<grid, 256, 0, stream>>>(tp, pp, acc);

    lddt_final<<<1, 1, 0, stream>>>(acc, out);
}

// Round 4
// 54.902 us; speedup vs baseline: 3.9704x; 1.3816x over previous
//
#include <hip/hip_runtime.h>
#include <hip/hip_bf16.h>

// SmoothLDDTLoss: b=2, n=4096
// inputs: pred_coords f32[2,4096,3], true_coords f32[2,4096,3],
//         is_dna i32[2,4096], is_rna i32[2,4096], coords_mask i32[2,4096]
// output: scalar f32 = 1 - mean_b(lddt_b)
//
// sigma(.5-d)+sigma(1-d)+sigma(2-d)+sigma(4-d) = t*Q'(t)/Q(t), t=e^{-d} (exact).
// Coords pre-scaled by log2(e) so t = exp2(-|dt_s - dp_s|) is a raw v_exp_f32.
// Diagonal (j==i) included in the pair loop, subtracted analytically at the end.

#define NRES 4096
#define NBATCH 2
#define TI 8

// scaled cutoffs: 15*log2(e), 30*log2(e)
#define CUT15 21.6404256133f
#define CUT30 43.2808512267f

// Q coefficients: elementary symmetric polys of {e^0.5, e^1, e^2, e^4}
#define S1 66.35420923f
#define S2 678.60880385f
#define S3 2039.58217570f
#define S4 1808.04241445f
// Q'(t)/4 coefficients
#define QP1 16.58855231f
#define QP2 339.30440193f
#define QP3 1529.68663177f
#define QP4 1808.04241445f

// eps value of a diagonal pair (diff=0): (sig(.5)+sig(1)+sig(2)+sig(4))/4
#define DIAG_EPS 0.80408219445f
#define LOG2E 1.44269504089f

__global__ void pack_kernel(const float* __restrict__ pred,
                            const float* __restrict__ truec,
                            const int* __restrict__ dna,
                            const int* __restrict__ rna,
                            const int* __restrict__ cm,
                            float4* __restrict__ tp,
                            float4* __restrict__ pp,
                            float* __restrict__ acc)
{
    int idx = blockIdx.x * 256 + threadIdx.x;
    if (idx >= NRES * NBATCH) return;
    float nuc = ((dna[idx] | rna[idx]) != 0) ? 1.0f : 0.0f;
    float cmf = (cm[idx] != 0) ? 1.0f : 0.0f;
    tp[idx] = make_float4(truec[3*idx+0]*LOG2E, truec[3*idx+1]*LOG2E, truec[3*idx+2]*LOG2E, nuc);
    pp[idx] = make_float4(pred[3*idx+0]*LOG2E,  pred[3*idx+1]*LOG2E,  pred[3*idx+2]*LOG2E,  cmf);

    // per-batch count of valid rows (for diagonal correction); waves never
    // straddle a batch boundary (4096 % 64 == 0)
    float v = cmf;
    #pragma unroll
    for (int o = 32; o > 0; o >>= 1) v += __shfl_down(v, o, 64);
    if ((threadIdx.x & 63) == 0) atomicAdd(&acc[4 + (idx >> 12)], v);
}

__launch_bounds__(256, 4)
__global__ void lddt_main(const float4* __restrict__ tp,
                          const float4* __restrict__ pp,
                          float* __restrict__ acc)  // [0..1] sums, [2..3] counts, [4..5] row counts
{
    const int b    = blockIdx.y;
    const int i0   = blockIdx.x * TI;
    const int base = b * NRES;
    const int tid  = threadIdx.x;

    float tix[TI], tiy[TI], tiz[TI];
    float pix[TI], piy[TI], piz[TI];
    float cHi[TI], cLo[TI];
    #pragma unroll
    for (int r = 0; r < TI; ++r) {
        float4 t4 = tp[base + i0 + r];
        float4 p4 = pp[base + i0 + r];
        tix[r] = t4.x; tiy[r] = t4.y; tiz[r] = t4.z;
        pix[r] = p4.x; piy[r] = p4.y; piz[r] = p4.z;
        bool cmi  = (p4.w != 0.0f);
        bool nuci = (t4.w != 0.0f);
        cHi[r] = cmi ? (nuci ? CUT30 : CUT15) : -1.0f;
        cLo[r] = cmi ? CUT15 : -1.0f;
    }

    float s = 0.0f, c = 0.0f;

    float4 t4 = tp[base + tid];
    float4 p4 = pp[base + tid];

    #pragma unroll 1
    for (int jt = 0; jt < NRES / 256; ++jt) {
        // prefetch next tile (wrap keeps addresses in-bounds; last iter reloads tile 0)
        const int jn = tid + (((jt + 1) & 15) << 8);
        float4 t4n = tp[base + jn];
        float4 p4n = pp[base + jn];

        const float wj   = p4.w;
        const bool  nucj = (t4.w != 0.0f);

        #pragma unroll
        for (int r = 0; r < TI; ++r) {
            float dx = tix[r] - t4.x, dy = tiy[r] - t4.y, dz = tiz[r] - t4.z;
            float dt = __builtin_amdgcn_sqrtf(dx*dx + dy*dy + dz*dz);
            float ex = pix[r] - p4.x, ey = piy[r] - p4.y, ez = piz[r] - p4.z;
            float dp = __builtin_amdgcn_sqrtf(ex*ex + ey*ey + ez*ez);

            float cutoff = nucj ? cHi[r] : cLo[r];
            float mf = (dt < cutoff) ? wj : 0.0f;

            float t = __builtin_amdgcn_exp2f(-fabsf(dt - dp));  // v_exp_f32, -abs modifier
            float Q  = 1.0f + t*(S1 + t*(S2 + t*(S3 + t*S4)));
            float Qp = QP1 + t*(QP2 + t*(QP3 + t*QP4)); // Q'(t)/4
            float rq = __builtin_amdgcn_rcpf(Q);

            s += mf * ((t * Qp) * rq);
            c += mf;
        }

        t4 = t4n; p4 = p4n;
    }

    // wave (64-lane) reduction
    #pragma unroll
    for (int o = 32; o > 0; o >>= 1) {
        s += __shfl_down(s, o, 64);
        c += __shfl_down(c, o, 64);
    }

    __shared__ float red_s[4];
    __shared__ float red_c[4];
    const int wid  = tid >> 6;
    const int lane = tid & 63;
    if (lane == 0) { red_s[wid] = s; red_c[wid] = c; }
    __syncthreads();

    if (tid == 0) {
        float ts = red_s[0] + red_s[1] + red_s[2] + red_s[3];
        float tc = red_c[0] + red_c[1] + red_c[2] + red_c[3];
        atomicAdd(&acc[b], ts);
        atomicAdd(&acc[NBATCH + b], tc);
    }
}

__global__ void lddt_final(const float* __restrict__ acc, float* __restrict__ out)
{
    float M0 = acc[4], M1 = acc[5];
    float l0 = (acc[0] - DIAG_EPS * M0) / fmaxf(acc[2] - M0, 1.0f);
    float l1 = (acc[1] - DIAG_EPS * M1) / fmaxf(acc[3] - M1, 1.0f);
    out[0] = 1.0f - 0.5f * (l0 + l1);
}

extern "C" void kernel_launch(void* const* d_in, const int* in_sizes, int n_in,
                              void* d_out, int out_size, void* d_ws, size_t ws_size,
                              hipStream_t stream) {
    const float* pred  = (const float*)d_in[0];
    const float* truec = (const float*)d_in[1];
    const int*   dna   = (const int*)d_in[2];
    const int*   rna   = (const int*)d_in[3];
    const int*   cmask = (const int*)d_in[4];
    float* out = (float*)d_out;

    char* ws = (char*)d_ws;
    float*  acc = (float*)ws;                         // 6 floats used
    float4* tp  = (float4*)(ws + 1024);               // 2*4096*16 B
    float4* pp  = (float4*)(ws + 1024 + NBATCH*NRES*16);

    (void)hipMemsetAsync(acc, 0, 8 * sizeof(float), stream);

    pack_kernel<<<(NRES*NBATCH + 255)/256, 256, 0, stream>>>(pred, truec, dna, rna, cmask, tp, pp, acc);

    dim3 grid(NRES / TI, NBATCH);
    lddt_main<<<grid, 256, 0, stream>>>(tp, pp, acc);

    lddt_final<<<1, 1, 0, stream>>>(acc, out);
}